// Round 7
// baseline (410.939 us; speedup 1.0000x reference)
//
#include <hip/hip_runtime.h>
#include <math.h>
#include <cstddef>

// Problem constants
#define BB 2
#define TT 2048
#define CC 2048
#define HH 16
#define HD 128
#define MM (BB * TT)   // 4096 tokens
#define QKV_N 6144
#define BK 32

typedef __attribute__((ext_vector_type(8))) short short8;
typedef __attribute__((ext_vector_type(4))) float f32x4;

__device__ __forceinline__ unsigned short f2bf(float f) {
    union { float f; unsigned int u; } v; v.f = f;
    unsigned int r = v.u + 0x7FFFu + ((v.u >> 16) & 1u);  // RNE
    return (unsigned short)(r >> 16);
}
__device__ __forceinline__ float bf2f(unsigned short s) {
    union { unsigned int u; float f; } v; v.u = ((unsigned int)s) << 16;
    return v.f;
}
__device__ __forceinline__ void gload16(const void* g, void* l) {
    __builtin_amdgcn_global_load_lds(
        (const __attribute__((address_space(1))) unsigned int*)g,
        (__attribute__((address_space(3))) unsigned int*)l, 16, 0, 0);
}

// ---------------------------------------------------------------------------
// K1: gating (fp32, argmax ties must match np) + fused x -> bf16 conversion.
// ---------------------------------------------------------------------------
__global__ __launch_bounds__(256) void gate_kernel(const float* __restrict__ x,
                                                   const float* __restrict__ Wg,
                                                   int* __restrict__ idxbuf,
                                                   float* __restrict__ top1buf,
                                                   unsigned short* __restrict__ xb) {
    int m = blockIdx.x;
    int tid = threadIdx.x;
    int h = tid >> 4;
    int j = tid & 15;
    const float4* xr = (const float4*)(x + (size_t)m * CC);
    const float4* wr = (const float4*)(Wg + (size_t)h * CC);
    float acc = 0.f;
#pragma unroll 8
    for (int i = 0; i < CC / 4; i += 16) {
        float4 a = xr[i + j];
        float4 b = wr[i + j];
        acc += a.x * b.x + a.y * b.y + a.z * b.z + a.w * b.w;
    }
    for (int off = 8; off > 0; off >>= 1) acc += __shfl_down(acc, off, 16);
    __shared__ float logits[HH];
    if (j == 0) logits[h] = acc;
    // fused bf16 conversion of this token row (L1-hot re-read)
    {
        float4 a = xr[tid * 2], b = xr[tid * 2 + 1];
        union { unsigned short s[8]; uint4 u; } pk;
        pk.s[0] = f2bf(a.x); pk.s[1] = f2bf(a.y); pk.s[2] = f2bf(a.z); pk.s[3] = f2bf(a.w);
        pk.s[4] = f2bf(b.x); pk.s[5] = f2bf(b.y); pk.s[6] = f2bf(b.z); pk.s[7] = f2bf(b.w);
        ((uint4*)(xb + (size_t)m * CC))[tid] = pk.u;
    }
    __syncthreads();
    if (tid == 0) {
        float zmax = logits[0];
        int best = 0;
        for (int i = 1; i < HH; i++) {
            if (logits[i] > zmax) { zmax = logits[i]; best = i; }
        }
        float s = 0.f;
        for (int i = 0; i < HH; i++) s += expf(logits[i] - zmax);
        idxbuf[m] = best;
        top1buf[m] = 1.0f / s;
    }
}

// ---------------------------------------------------------------------------
// K2: fp32 -> bf16 convert (for W_qkv).
// ---------------------------------------------------------------------------
__global__ __launch_bounds__(256) void convert_bf16(const float* __restrict__ src,
                                                    unsigned short* __restrict__ dst,
                                                    int n8) {
    int i = blockIdx.x * 256 + threadIdx.x;
    if (i >= n8) return;
    const float4* s4 = (const float4*)src;
    float4 a = s4[i * 2], b = s4[i * 2 + 1];
    union { unsigned short s[8]; uint4 u; } pk;
    pk.s[0] = f2bf(a.x); pk.s[1] = f2bf(a.y); pk.s[2] = f2bf(a.z); pk.s[3] = f2bf(a.w);
    pk.s[4] = f2bf(b.x); pk.s[5] = f2bf(b.y); pk.s[6] = f2bf(b.z); pk.s[7] = f2bf(b.w);
    ((uint4*)dst)[i] = pk.u;
}

// ---------------------------------------------------------------------------
// K3: q = xb @ wb[0:2048]^T, bf16 MFMA GEMM (m97 structure), pre-scaled.
// Output [M][2048] bf16. (k/v columns are NOT computed here — only each
// token's selected head's k/v is needed; see bucket + kvsel below.)
// ---------------------------------------------------------------------------
__global__ __launch_bounds__(256) void qproj_gemm(const unsigned short* __restrict__ A,  // [M][2048] bf16
                                                  const unsigned short* __restrict__ Bm, // wb [6144][2048]
                                                  unsigned short* __restrict__ C) {      // [M][2048] bf16
    __shared__ unsigned short As[128 * BK];
    __shared__ unsigned short Bs[128 * BK];
    int tid = threadIdx.x;
    int wave = tid >> 6, lane = tid & 63;
    int l = lane & 15, g = lane >> 4;
    int m0 = blockIdx.y * 128, n0 = blockIdx.x * 128;
    int wr = wave >> 1, wc = wave & 1;

    f32x4 acc[4][4];
#pragma unroll
    for (int i = 0; i < 4; i++)
#pragma unroll
        for (int j = 0; j < 4; j++) acc[i][j] = (f32x4){0.f, 0.f, 0.f, 0.f};

    int srow = lane >> 2;
    int scol = (lane & 3) * 8;
    const unsigned short* aB0 = A + (size_t)(m0 + wave * 32 + srow) * 2048 + scol;
    const unsigned short* bB0 = Bm + (size_t)(n0 + wave * 32 + srow) * 2048 + scol;
    unsigned short* aL0 = &As[wave * 1024];
    unsigned short* bL0 = &Bs[wave * 1024];

    for (int k0 = 0; k0 < 2048; k0 += BK) {
        __syncthreads();
        gload16(aB0 + k0, aL0);
        gload16(aB0 + k0 + (size_t)16 * 2048, aL0 + 512);
        gload16(bB0 + k0, bL0);
        gload16(bB0 + k0 + (size_t)16 * 2048, bL0 + 512);
        __syncthreads();
        short8 af[4], bf[4];
#pragma unroll
        for (int i = 0; i < 4; i++)
            af[i] = *(const short8*)&As[(wr * 64 + i * 16 + l) * BK + g * 8];
#pragma unroll
        for (int j = 0; j < 4; j++)
            bf[j] = *(const short8*)&Bs[(wc * 64 + j * 16 + l) * BK + g * 8];
#pragma unroll
        for (int i = 0; i < 4; i++)
#pragma unroll
            for (int j = 0; j < 4; j++)
                acc[i][j] = __builtin_amdgcn_mfma_f32_16x16x32_bf16(af[i], bf[j], acc[i][j], 0, 0, 0);
    }

    const float qscale = 0.08838834764831845f;  // 1/sqrt(128)
#pragma unroll
    for (int j = 0; j < 4; j++) {
        int col = n0 + wc * 64 + j * 16 + l;
#pragma unroll
        for (int i = 0; i < 4; i++) {
            int row = m0 + wr * 64 + i * 16 + g * 4;
#pragma unroll
            for (int r = 0; r < 4; r++)
                C[(size_t)(row + r) * CC + col] = f2bf(acc[i][j][r] * qscale);
        }
    }
}

// ---------------------------------------------------------------------------
// K4: bucket tokens by selected head. One block. ord[] = token ids grouped by
// head (stable order, but any order is correct); hs[17] = bucket starts.
// ---------------------------------------------------------------------------
__global__ __launch_bounds__(256) void bucket_kernel(const int* __restrict__ idxb,
                                                     int* __restrict__ ord,
                                                     int* __restrict__ hs) {
    __shared__ unsigned short cnts[256][16];   // 8 KB
    __shared__ int hsum[16], hbase[16];
    int t = threadIdx.x;
    unsigned short c[16];
#pragma unroll
    for (int h = 0; h < 16; h++) c[h] = 0;
    int hv[16];
#pragma unroll
    for (int i = 0; i < 16; i++) {
        hv[i] = idxb[t * 16 + i];
        c[hv[i]]++;
    }
#pragma unroll
    for (int h = 0; h < 16; h++) cnts[t][h] = c[h];
    __syncthreads();
    if (t < 16) {   // per-head exclusive prefix over 256 threads
        int s = 0;
        for (int j = 0; j < 256; j++) {
            int v = cnts[j][t];
            cnts[j][t] = (unsigned short)s;  // fits: <= 4096? no: per-thread prefix can reach 4096
            s += v;
        }
        hsum[t] = s;
    }
    __syncthreads();
    if (t == 0) {
        int s = 0;
        for (int h = 0; h < 16; h++) { hbase[h] = s; hs[h] = s; s += hsum[h]; }
        hs[16] = s;
    }
    __syncthreads();
    int pos[16];
#pragma unroll
    for (int h = 0; h < 16; h++) pos[h] = hbase[h] + (int)cnts[t][h];
#pragma unroll
    for (int i = 0; i < 16; i++) {
        int h = hv[i];
        ord[pos[h]++] = t * 16 + i;
    }
}

// ---------------------------------------------------------------------------
// K5: selected-head k/v projection, bucketed MFMA GEMM.
// grid (16 heads, 2 regions[k|v], 64 m-tiles); empty tiles early-exit.
// Block: 64 gathered token rows x 128 cols, K=2048, BK=32.
//   reg==0: kshB[tok][d] = x_tok . Wk_head_d
//   reg==1: vshT[d][tok] = top1 * (x_tok . Wv_head_d)
// ---------------------------------------------------------------------------
__global__ __launch_bounds__(256) void kvsel_gemm(const unsigned short* __restrict__ xb,
                                                  const unsigned short* __restrict__ wb,
                                                  const int* __restrict__ ord,
                                                  const int* __restrict__ hs,
                                                  const float* __restrict__ top1,
                                                  unsigned short* __restrict__ kshB,
                                                  unsigned short* __restrict__ vshT) {
    __shared__ unsigned short As[64 * 32];    // 4 KB
    __shared__ unsigned short Bs[128 * 32];   // 8 KB
    int h = blockIdx.x, reg = blockIdx.y, mt = blockIdx.z;
    int s0 = hs[h], s1 = hs[h + 1];
    int cnt = s1 - s0;
    if (mt * 64 >= cnt) return;
    int base = s0 + mt * 64;
    int tid = threadIdx.x;
    int wave = tid >> 6, lane = tid & 63;
    int l = lane & 15, g = lane >> 4;

    // staging pointers (fixed rows across K loop)
    int arow = base + wave * 16 + (lane >> 2);
    int atok = ord[(arow < s1) ? arow : (s1 - 1)];
    const unsigned short* aSrc = xb + (size_t)atok * CC + (lane & 3) * 8;
    unsigned short* aDst = &As[wave * 512];
    int wr0 = 2048 + reg * 2048 + h * 128;    // W row base for this region
    const unsigned short* bSrc0 = wb + (size_t)(wr0 + (wave * 2 + 0) * 16 + (lane >> 2)) * CC + (lane & 3) * 8;
    const unsigned short* bSrc1 = wb + (size_t)(wr0 + (wave * 2 + 1) * 16 + (lane >> 2)) * CC + (lane & 3) * 8;
    unsigned short* bDst0 = &Bs[(wave * 2 + 0) * 512];
    unsigned short* bDst1 = &Bs[(wave * 2 + 1) * 512];

    f32x4 acc[8];
#pragma unroll
    for (int j = 0; j < 8; j++) acc[j] = (f32x4){0.f, 0.f, 0.f, 0.f};

    for (int k0 = 0; k0 < 2048; k0 += 32) {
        __syncthreads();
        gload16(aSrc + k0, aDst);
        gload16(bSrc0 + k0, bDst0);
        gload16(bSrc1 + k0, bDst1);
        __syncthreads();
        short8 af = *(const short8*)&As[(wave * 16 + l) * 32 + g * 8];
#pragma unroll
        for (int j = 0; j < 8; j++) {
            short8 bf = *(const short8*)&Bs[(j * 16 + l) * 32 + g * 8];
            acc[j] = __builtin_amdgcn_mfma_f32_16x16x32_bf16(af, bf, acc[j], 0, 0, 0);
        }
    }
#pragma unroll
    for (int i = 0; i < 4; i++) {
        int r = wave * 16 + g * 4 + i;
        if (base + r >= s1) continue;
        int tok = ord[base + r];
        if (reg == 0) {
#pragma unroll
            for (int j = 0; j < 8; j++)
                kshB[(size_t)tok * HD + j * 16 + l] = f2bf(acc[j][i]);
        } else {
            float tv = top1[tok];
#pragma unroll
            for (int j = 0; j < 8; j++)
                vshT[(size_t)(j * 16 + l) * MM + tok] = f2bf(acc[j][i] * tv);
        }
    }
}

// ---------------------------------------------------------------------------
// K6: MFMA bf16 flash attention, MQA head-sharing (8 heads/block, 2/wave).
// Changes vs R6: K/V frag LDS reads hoisted out of the head loop (halved LDS
// traffic); next chunk's K/V staged via register prefetch issued right after
// the barrier (L2 latency hides behind compute); dual-head Ps buffer.
// ---------------------------------------------------------------------------
__global__ __launch_bounds__(256, 2) void attn_mfma(const unsigned short* __restrict__ qb,   // [M][2048] bf16 pre-scaled
                                                    const unsigned short* __restrict__ kb,   // [M][128] bf16
                                                    const unsigned short* __restrict__ vtb,  // [128][M] bf16
                                                    float* __restrict__ y) {                 // [M][2048] fp32
    __shared__ unsigned short Ks[64][136];        // 17408 B
    __shared__ unsigned short Vt[128][72];        // 18432 B
    __shared__ unsigned short Ps[4][2][16][72];   // 18432 B (per-wave, 2 heads)

    int bid = blockIdx.x;                 // 512 blocks
    int qq = 127 - (bid >> 2);            // 16-row q-tile, longest first
    int b  = (bid >> 1) & 1;
    int hh = bid & 1;
    int q0 = qq * 16;
    int nch = (qq >> 2) + 1;
    int tid = threadIdx.x;
    int wave = tid >> 6;
    int lane = tid & 63;
    int l = lane & 15;
    int g = lane >> 4;
    int h0 = hh * 8 + wave * 2;

    short8 qf[2][4];
    {
        const unsigned short* qrow = qb + (size_t)(b * TT + q0 + l) * CC;
#pragma unroll
        for (int hd2 = 0; hd2 < 2; hd2++)
#pragma unroll
            for (int kc = 0; kc < 4; kc++)
                qf[hd2][kc] = *(const short8*)(qrow + (h0 + hd2) * HD + kc * 32 + g * 8);
    }
    short8 onesf;
    {
        short v = (l == 0) ? (short)0x3F80 : (short)0;
#pragma unroll
        for (int e = 0; e < 8; e++) onesf[e] = v;
    }

    f32x4 o[2][8];
    f32x4 o8[2];
#pragma unroll
    for (int hd2 = 0; hd2 < 2; hd2++) {
#pragma unroll
        for (int n = 0; n < 8; n++) o[hd2][n] = (f32x4){0.f, 0.f, 0.f, 0.f};
        o8[hd2] = (f32x4){0.f, 0.f, 0.f, 0.f};
    }

    const unsigned short* kbase = kb + (size_t)b * TT * HD;
    int rbase = q0 + g * 4;

    // staging map (fixed per thread)
    int krow[4], kcol[4], vdd[4], vk8[4];
#pragma unroll
    for (int rep = 0; rep < 4; rep++) {
        int f = tid + rep * 256;
        krow[rep] = f >> 4;  kcol[rep] = (f & 15) * 8;
        vdd[rep]  = f >> 3;  vk8[rep]  = (f & 7) * 8;
    }
    uint4 kreg[4], vreg[4];
#pragma unroll
    for (int rep = 0; rep < 4; rep++) {
        kreg[rep] = *(const uint4*)(kbase + (size_t)krow[rep] * HD + kcol[rep]);
        vreg[rep] = *(const uint4*)(vtb + (size_t)vdd[rep] * MM + b * TT + vk8[rep]);
    }

    for (int c = 0; c < nch; c++) {
        int kc0 = c * 64;
        __syncthreads();   // previous chunk's LDS reads done
#pragma unroll
        for (int rep = 0; rep < 4; rep++) *(uint4*)&Ks[krow[rep]][kcol[rep]] = kreg[rep];
#pragma unroll
        for (int rep = 0; rep < 4; rep++) *(uint4*)&Vt[vdd[rep]][vk8[rep]] = vreg[rep];
        __syncthreads();   // staging visible
        if (c + 1 < nch) { // prefetch next chunk (latency hides behind compute)
            int nk = kc0 + 64;
#pragma unroll
            for (int rep = 0; rep < 4; rep++) {
                kreg[rep] = *(const uint4*)(kbase + (size_t)(nk + krow[rep]) * HD + kcol[rep]);
                vreg[rep] = *(const uint4*)(vtb + (size_t)vdd[rep] * MM + b * TT + nk + vk8[rep]);
            }
        }

        // S = Q K^T (K frags read once, used by both heads)
        f32x4 st[2][4];
#pragma unroll
        for (int t = 0; t < 4; t++) {
            short8 kf[4];
#pragma unroll
            for (int kc = 0; kc < 4; kc++)
                kf[kc] = *(const short8*)&Ks[t * 16 + l][kc * 32 + g * 8];
#pragma unroll
            for (int hd2 = 0; hd2 < 2; hd2++) {
                f32x4 a = (f32x4){0.f, 0.f, 0.f, 0.f};
#pragma unroll
                for (int kc = 0; kc < 4; kc++)
                    a = __builtin_amdgcn_mfma_f32_16x16x32_bf16(qf[hd2][kc], kf[kc], a, 0, 0, 0);
                st[hd2][t] = a;
            }
        }
        if (c == nch - 1) {  // diagonal chunk: causal mask
#pragma unroll
            for (int t = 0; t < 4; t++) {
                int key = kc0 + t * 16 + l;
#pragma unroll
                for (int i = 0; i < 4; i++)
                    if (key > rbase + i) { st[0][t][i] = -1e30f; st[1][t][i] = -1e30f; }
            }
        }
        // p = exp(s - 30) -> Ps (A-layout); per-wave, same-wave DS ordering
#pragma unroll
        for (int hd2 = 0; hd2 < 2; hd2++)
#pragma unroll
            for (int t = 0; t < 4; t++)
#pragma unroll
                for (int i = 0; i < 4; i++)
                    Ps[wave][hd2][g * 4 + i][t * 16 + l] = f2bf(__expf(st[hd2][t][i] - 30.f));
        // O += P V ; l += P (V frags read once, used by both heads)
#pragma unroll
        for (int kc2 = 0; kc2 < 2; kc2++) {
            short8 pf0 = *(const short8*)&Ps[wave][0][l][kc2 * 32 + g * 8];
            short8 pf1 = *(const short8*)&Ps[wave][1][l][kc2 * 32 + g * 8];
#pragma unroll
            for (int n = 0; n < 8; n++) {
                short8 vf = *(const short8*)&Vt[n * 16 + l][kc2 * 32 + g * 8];
                o[0][n] = __builtin_amdgcn_mfma_f32_16x16x32_bf16(pf0, vf, o[0][n], 0, 0, 0);
                o[1][n] = __builtin_amdgcn_mfma_f32_16x16x32_bf16(pf1, vf, o[1][n], 0, 0, 0);
            }
            o8[0] = __builtin_amdgcn_mfma_f32_16x16x32_bf16(pf0, onesf, o8[0], 0, 0, 0);
            o8[1] = __builtin_amdgcn_mfma_f32_16x16x32_bf16(pf1, onesf, o8[1], 0, 0, 0);
        }
    }
#pragma unroll
    for (int hd2 = 0; hd2 < 2; hd2++) {
        float inv[4];
#pragma unroll
        for (int i = 0; i < 4; i++) {
            float lv = __shfl(o8[hd2][i], lane & 48);
            inv[i] = 1.f / lv;
        }
#pragma unroll
        for (int n = 0; n < 8; n++) {
#pragma unroll
            for (int i = 0; i < 4; i++) {
                y[(size_t)(b * TT + q0 + g * 4 + i) * CC + (h0 + hd2) * HD + n * 16 + l] =
                    o[hd2][n][i] * inv[i];
            }
        }
    }
}

// ---------------------------------------------------------------------------
// Launcher. Workspace (~62 MB):
//   xb [M*2048]u16, wb [6144*2048]u16, qbuf [M*2048]u16,
//   kshB [M*128]u16, vshT [128*M]u16, top1 f32[M], idxb i32[M],
//   ord i32[M], hs i32[17]
// ---------------------------------------------------------------------------
extern "C" void kernel_launch(void* const* d_in, const int* in_sizes, int n_in,
                              void* d_out, int out_size, void* d_ws, size_t ws_size,
                              hipStream_t stream) {
    (void)in_sizes; (void)n_in; (void)out_size; (void)ws_size;
    const float* x    = (const float*)d_in[0];
    const float* Wg   = (const float*)d_in[1];
    const float* Wqkv = (const float*)d_in[2];
    float* y = (float*)d_out;

    unsigned short* xb   = (unsigned short*)d_ws;
    unsigned short* wb   = xb + (size_t)MM * CC;
    unsigned short* qbuf = wb + (size_t)QKV_N * CC;
    unsigned short* kshB = qbuf + (size_t)MM * CC;
    unsigned short* vshT = kshB + (size_t)MM * HD;
    float* top1 = (float*)(vshT + (size_t)HD * MM);
    int*   idxb = (int*)(top1 + MM);
    int*   ord  = idxb + MM;
    int*   hs   = ord + MM;

    gate_kernel<<<MM, 256, 0, stream>>>(x, Wg, idxb, top1, xb);
    convert_bf16<<<(QKV_N * CC / 8 + 255) / 256, 256, 0, stream>>>(Wqkv, wb, QKV_N * CC / 8);
    qproj_gemm<<<dim3(16, 32), 256, 0, stream>>>(xb, wb, qbuf);
    bucket_kernel<<<1, 256, 0, stream>>>(idxb, ord, hs);
    kvsel_gemm<<<dim3(16, 2, 64), 256, 0, stream>>>(xb, wb, ord, hs, top1, kshB, vshT);
    attn_mfma<<<512, 256, 0, stream>>>(qbuf, kshB, vshT, y);
}

// Round 9
// 364.091 us; speedup vs baseline: 1.1287x; 1.1287x over previous
//
#include <hip/hip_runtime.h>
#include <math.h>
#include <cstddef>

// Problem constants
#define BB 2
#define TT 2048
#define CC 2048
#define HH 16
#define HD 128
#define MM (BB * TT)   // 4096 tokens
#define QKV_N 6144
#define BK 32

typedef __attribute__((ext_vector_type(8))) short short8;
typedef __attribute__((ext_vector_type(4))) float f32x4;

__device__ __forceinline__ unsigned short f2bf(float f) {
    union { float f; unsigned int u; } v; v.f = f;
    unsigned int r = v.u + 0x7FFFu + ((v.u >> 16) & 1u);  // RNE
    return (unsigned short)(r >> 16);
}
__device__ __forceinline__ float bf2f(unsigned short s) {
    union { unsigned int u; float f; } v; v.u = ((unsigned int)s) << 16;
    return v.f;
}
__device__ __forceinline__ void gload16(const void* g, void* l) {
    __builtin_amdgcn_global_load_lds(
        (const __attribute__((address_space(1))) unsigned int*)g,
        (__attribute__((address_space(3))) unsigned int*)l, 16, 0, 0);
}

// ---------------------------------------------------------------------------
// K1: gating (fp32, argmax ties must match np) + fused x -> bf16 conversion.
// ---------------------------------------------------------------------------
__global__ __launch_bounds__(256) void gate_kernel(const float* __restrict__ x,
                                                   const float* __restrict__ Wg,
                                                   int* __restrict__ idxbuf,
                                                   float* __restrict__ top1buf,
                                                   unsigned short* __restrict__ xb) {
    int m = blockIdx.x;
    int tid = threadIdx.x;
    int h = tid >> 4;
    int j = tid & 15;
    const float4* xr = (const float4*)(x + (size_t)m * CC);
    const float4* wr = (const float4*)(Wg + (size_t)h * CC);
    float acc = 0.f;
#pragma unroll 8
    for (int i = 0; i < CC / 4; i += 16) {
        float4 a = xr[i + j];
        float4 b = wr[i + j];
        acc += a.x * b.x + a.y * b.y + a.z * b.z + a.w * b.w;
    }
    for (int off = 8; off > 0; off >>= 1) acc += __shfl_down(acc, off, 16);
    __shared__ float logits[HH];
    if (j == 0) logits[h] = acc;
    // fused bf16 conversion of this token row (L1-hot re-read)
    {
        float4 a = xr[tid * 2], b = xr[tid * 2 + 1];
        union { unsigned short s[8]; uint4 u; } pk;
        pk.s[0] = f2bf(a.x); pk.s[1] = f2bf(a.y); pk.s[2] = f2bf(a.z); pk.s[3] = f2bf(a.w);
        pk.s[4] = f2bf(b.x); pk.s[5] = f2bf(b.y); pk.s[6] = f2bf(b.z); pk.s[7] = f2bf(b.w);
        ((uint4*)(xb + (size_t)m * CC))[tid] = pk.u;
    }
    __syncthreads();
    if (tid == 0) {
        float zmax = logits[0];
        int best = 0;
        for (int i = 1; i < HH; i++) {
            if (logits[i] > zmax) { zmax = logits[i]; best = i; }
        }
        float s = 0.f;
        for (int i = 0; i < HH; i++) s += expf(logits[i] - zmax);
        idxbuf[m] = best;
        top1buf[m] = 1.0f / s;
    }
}

// ---------------------------------------------------------------------------
// K2: fp32 -> bf16 convert (for W_qkv).
// ---------------------------------------------------------------------------
__global__ __launch_bounds__(256) void convert_bf16(const float* __restrict__ src,
                                                    unsigned short* __restrict__ dst,
                                                    int n8) {
    int i = blockIdx.x * 256 + threadIdx.x;
    if (i >= n8) return;
    const float4* s4 = (const float4*)src;
    float4 a = s4[i * 2], b = s4[i * 2 + 1];
    union { unsigned short s[8]; uint4 u; } pk;
    pk.s[0] = f2bf(a.x); pk.s[1] = f2bf(a.y); pk.s[2] = f2bf(a.z); pk.s[3] = f2bf(a.w);
    pk.s[4] = f2bf(b.x); pk.s[5] = f2bf(b.y); pk.s[6] = f2bf(b.z); pk.s[7] = f2bf(b.w);
    ((uint4*)dst)[i] = pk.u;
}

// ---------------------------------------------------------------------------
// K3: q = xb @ wb[0:2048]^T, bf16 MFMA GEMM (m97 structure), pre-scaled.
// ---------------------------------------------------------------------------
__global__ __launch_bounds__(256) void qproj_gemm(const unsigned short* __restrict__ A,  // [M][2048] bf16
                                                  const unsigned short* __restrict__ Bm, // wb [6144][2048]
                                                  unsigned short* __restrict__ C) {      // [M][2048] bf16
    __shared__ unsigned short As[128 * BK];
    __shared__ unsigned short Bs[128 * BK];
    int tid = threadIdx.x;
    int wave = tid >> 6, lane = tid & 63;
    int l = lane & 15, g = lane >> 4;
    int m0 = blockIdx.y * 128, n0 = blockIdx.x * 128;
    int wr = wave >> 1, wc = wave & 1;

    f32x4 acc[4][4];
#pragma unroll
    for (int i = 0; i < 4; i++)
#pragma unroll
        for (int j = 0; j < 4; j++) acc[i][j] = (f32x4){0.f, 0.f, 0.f, 0.f};

    int srow = lane >> 2;
    int scol = (lane & 3) * 8;
    const unsigned short* aB0 = A + (size_t)(m0 + wave * 32 + srow) * 2048 + scol;
    const unsigned short* bB0 = Bm + (size_t)(n0 + wave * 32 + srow) * 2048 + scol;
    unsigned short* aL0 = &As[wave * 1024];
    unsigned short* bL0 = &Bs[wave * 1024];

    for (int k0 = 0; k0 < 2048; k0 += BK) {
        __syncthreads();
        gload16(aB0 + k0, aL0);
        gload16(aB0 + k0 + (size_t)16 * 2048, aL0 + 512);
        gload16(bB0 + k0, bL0);
        gload16(bB0 + k0 + (size_t)16 * 2048, bL0 + 512);
        __syncthreads();
        short8 af[4], bf[4];
#pragma unroll
        for (int i = 0; i < 4; i++)
            af[i] = *(const short8*)&As[(wr * 64 + i * 16 + l) * BK + g * 8];
#pragma unroll
        for (int j = 0; j < 4; j++)
            bf[j] = *(const short8*)&Bs[(wc * 64 + j * 16 + l) * BK + g * 8];
#pragma unroll
        for (int i = 0; i < 4; i++)
#pragma unroll
            for (int j = 0; j < 4; j++)
                acc[i][j] = __builtin_amdgcn_mfma_f32_16x16x32_bf16(af[i], bf[j], acc[i][j], 0, 0, 0);
    }

    const float qscale = 0.08838834764831845f;  // 1/sqrt(128)
#pragma unroll
    for (int j = 0; j < 4; j++) {
        int col = n0 + wc * 64 + j * 16 + l;
#pragma unroll
        for (int i = 0; i < 4; i++) {
            int row = m0 + wr * 64 + i * 16 + g * 4;
#pragma unroll
            for (int r = 0; r < 4; r++)
                C[(size_t)(row + r) * CC + col] = f2bf(acc[i][j][r] * qscale);
        }
    }
}

// ---------------------------------------------------------------------------
// K4: bucket tokens by selected head (one block).
// ---------------------------------------------------------------------------
__global__ __launch_bounds__(256) void bucket_kernel(const int* __restrict__ idxb,
                                                     int* __restrict__ ord,
                                                     int* __restrict__ hs) {
    __shared__ unsigned short cnts[256][16];
    __shared__ int hsum[16], hbase[16];
    int t = threadIdx.x;
    unsigned short c[16];
#pragma unroll
    for (int h = 0; h < 16; h++) c[h] = 0;
    int hv[16];
#pragma unroll
    for (int i = 0; i < 16; i++) {
        hv[i] = idxb[t * 16 + i];
        c[hv[i]]++;
    }
#pragma unroll
    for (int h = 0; h < 16; h++) cnts[t][h] = c[h];
    __syncthreads();
    if (t < 16) {
        int s = 0;
        for (int j = 0; j < 256; j++) {
            int v = cnts[j][t];
            cnts[j][t] = (unsigned short)s;
            s += v;
        }
        hsum[t] = s;
    }
    __syncthreads();
    if (t == 0) {
        int s = 0;
        for (int h = 0; h < 16; h++) { hbase[h] = s; hs[h] = s; s += hsum[h]; }
        hs[16] = s;
    }
    __syncthreads();
    int pos[16];
#pragma unroll
    for (int h = 0; h < 16; h++) pos[h] = hbase[h] + (int)cnts[t][h];
#pragma unroll
    for (int i = 0; i < 16; i++) {
        int h = hv[i];
        ord[pos[h]++] = t * 16 + i;
    }
}

// ---------------------------------------------------------------------------
// K5: selected-head k/v projection, bucketed MFMA GEMM.
// ---------------------------------------------------------------------------
__global__ __launch_bounds__(256) void kvsel_gemm(const unsigned short* __restrict__ xb,
                                                  const unsigned short* __restrict__ wb,
                                                  const int* __restrict__ ord,
                                                  const int* __restrict__ hs,
                                                  const float* __restrict__ top1,
                                                  unsigned short* __restrict__ kshB,
                                                  unsigned short* __restrict__ vshT) {
    __shared__ unsigned short As[64 * 32];
    __shared__ unsigned short Bs[128 * 32];
    int h = blockIdx.x, reg = blockIdx.y, mt = blockIdx.z;
    int s0 = hs[h], s1 = hs[h + 1];
    int cnt = s1 - s0;
    if (mt * 64 >= cnt) return;
    int base = s0 + mt * 64;
    int tid = threadIdx.x;
    int wave = tid >> 6, lane = tid & 63;
    int l = lane & 15, g = lane >> 4;

    int arow = base + wave * 16 + (lane >> 2);
    int atok = ord[(arow < s1) ? arow : (s1 - 1)];
    const unsigned short* aSrc = xb + (size_t)atok * CC + (lane & 3) * 8;
    unsigned short* aDst = &As[wave * 512];
    int wr0 = 2048 + reg * 2048 + h * 128;
    const unsigned short* bSrc0 = wb + (size_t)(wr0 + (wave * 2 + 0) * 16 + (lane >> 2)) * CC + (lane & 3) * 8;
    const unsigned short* bSrc1 = wb + (size_t)(wr0 + (wave * 2 + 1) * 16 + (lane >> 2)) * CC + (lane & 3) * 8;
    unsigned short* bDst0 = &Bs[(wave * 2 + 0) * 512];
    unsigned short* bDst1 = &Bs[(wave * 2 + 1) * 512];

    f32x4 acc[8];
#pragma unroll
    for (int j = 0; j < 8; j++) acc[j] = (f32x4){0.f, 0.f, 0.f, 0.f};

    for (int k0 = 0; k0 < 2048; k0 += 32) {
        __syncthreads();
        gload16(aSrc + k0, aDst);
        gload16(bSrc0 + k0, bDst0);
        gload16(bSrc1 + k0, bDst1);
        __syncthreads();
        short8 af = *(const short8*)&As[(wave * 16 + l) * 32 + g * 8];
#pragma unroll
        for (int j = 0; j < 8; j++) {
            short8 bf = *(const short8*)&Bs[(j * 16 + l) * 32 + g * 8];
            acc[j] = __builtin_amdgcn_mfma_f32_16x16x32_bf16(af, bf, acc[j], 0, 0, 0);
        }
    }
#pragma unroll
    for (int i = 0; i < 4; i++) {
        int r = wave * 16 + g * 4 + i;
        if (base + r >= s1) continue;
        int tok = ord[base + r];
        if (reg == 0) {
#pragma unroll
            for (int j = 0; j < 8; j++)
                kshB[(size_t)tok * HD + j * 16 + l] = f2bf(acc[j][i]);
        } else {
            float tv = top1[tok];
#pragma unroll
            for (int j = 0; j < 8; j++)
                vshT[(size_t)(j * 16 + l) * MM + tok] = f2bf(acc[j][i] * tv);
        }
    }
}

// ---------------------------------------------------------------------------
// K6: MFMA bf16 flash attention — EXACT Round-6 proven body (two barriers,
// single K/V buffer, 8 heads/block with 2 sequential heads/wave, fixed-shift
// softmax, ones-column row-sum). Only change: q stride QKV_N -> CC.
// ---------------------------------------------------------------------------
__global__ __launch_bounds__(256) void attn_mfma(const unsigned short* __restrict__ qb,   // [M][2048] bf16, q pre-scaled
                                                 const unsigned short* __restrict__ kb,   // [M][128] bf16
                                                 const unsigned short* __restrict__ vtb,  // [128][M] bf16
                                                 float* __restrict__ y) {                 // [M][2048] fp32
    __shared__ unsigned short Ks[64][136];   // 17408 B
    __shared__ unsigned short Vt[128][72];   // 18432 B
    __shared__ unsigned short Ps[4][16][72]; //  9216 B (per-wave)

    int bid = blockIdx.x;                 // 512 blocks
    int qq = 127 - (bid >> 2);            // 16-row q-tile, longest first
    int b  = (bid >> 1) & 1;
    int hh = bid & 1;                     // head half
    int q0 = qq * 16;
    int nch = (qq >> 2) + 1;              // 64-key chunks
    int tid = threadIdx.x;
    int wave = tid >> 6;
    int lane = tid & 63;
    int l = lane & 15;
    int g = lane >> 4;
    int h0 = hh * 8 + wave * 2;           // this wave's first head

    // Q a-frags for 2 heads (bf16, pre-scaled)
    short8 qf[2][4];
    {
        const unsigned short* qrow = qb + (size_t)(b * TT + q0 + l) * CC;
#pragma unroll
        for (int hd2 = 0; hd2 < 2; hd2++)
#pragma unroll
            for (int kc = 0; kc < 4; kc++)
                qf[hd2][kc] = *(const short8*)(qrow + (h0 + hd2) * HD + kc * 32 + g * 8);
    }

    // ones-column B-frag: B[n][k] = (n==0) ? 1 : 0
    short8 onesf;
    {
        short v = (l == 0) ? (short)0x3F80 : (short)0;
#pragma unroll
        for (int e = 0; e < 8; e++) onesf[e] = v;
    }

    f32x4 o[2][8];
    f32x4 o8[2];
#pragma unroll
    for (int hd2 = 0; hd2 < 2; hd2++) {
#pragma unroll
        for (int n = 0; n < 8; n++) o[hd2][n] = (f32x4){0.f, 0.f, 0.f, 0.f};
        o8[hd2] = (f32x4){0.f, 0.f, 0.f, 0.f};
    }

    const unsigned short* kbase = kb + (size_t)b * TT * HD;
    int rbase = q0 + g * 4;

    for (int c = 0; c < nch; c++) {
        int kc0 = c * 64;
        __syncthreads();   // previous chunk's LDS reads done
        // stage K: 64 keys x 128 dims, 1024 uint4, coalesced (1KB rows)
#pragma unroll
        for (int rep = 0; rep < 4; rep++) {
            int f = tid + rep * 256;
            int row = f >> 4, c8 = f & 15;
            *(uint4*)&Ks[row][c8 * 8] =
                *(const uint4*)(kbase + (size_t)(kc0 + row) * HD + c8 * 8);
        }
        // stage Vt: 128 dims x 64 keys (transposed source, 128B segments)
#pragma unroll
        for (int rep = 0; rep < 4; rep++) {
            int f = tid + rep * 256;
            int dd = f >> 3, k8 = f & 7;
            *(uint4*)&Vt[dd][k8 * 8] =
                *(const uint4*)(vtb + (size_t)dd * MM + b * TT + kc0 + k8 * 8);
        }
        __syncthreads();
        bool diag = (c == nch - 1);

#pragma unroll
        for (int hd2 = 0; hd2 < 2; hd2++) {
            // S = Q K^T
            f32x4 st[4];
#pragma unroll
            for (int t = 0; t < 4; t++) {
                f32x4 acc = (f32x4){0.f, 0.f, 0.f, 0.f};
#pragma unroll
                for (int kc = 0; kc < 4; kc++) {
                    short8 bfr = *(const short8*)&Ks[t * 16 + l][kc * 32 + g * 8];
                    acc = __builtin_amdgcn_mfma_f32_16x16x32_bf16(qf[hd2][kc], bfr, acc, 0, 0, 0);
                }
                st[t] = acc;
            }
            if (diag) {  // causal mask, diagonal chunk only (wave-uniform)
#pragma unroll
                for (int t = 0; t < 4; t++) {
                    int key = kc0 + t * 16 + l;
#pragma unroll
                    for (int i = 0; i < 4; i++)
                        if (key > rbase + i) st[t][i] = -1e30f;
                }
            }
            // p = exp(s - 30) -> Ps (A-layout); per-wave buffer, same-wave
            // DS ordering makes write->read and head0->head1 reuse safe.
#pragma unroll
            for (int t = 0; t < 4; t++) {
#pragma unroll
                for (int i = 0; i < 4; i++) {
                    float p = __expf(st[t][i] - 30.f);
                    Ps[wave][g * 4 + i][t * 16 + l] = f2bf(p);
                }
            }
            // O += P V ; l += P (ones column)
#pragma unroll
            for (int kc2 = 0; kc2 < 2; kc2++) {
                short8 pf = *(const short8*)&Ps[wave][l][kc2 * 32 + g * 8];
#pragma unroll
                for (int n = 0; n < 8; n++) {
                    short8 vf = *(const short8*)&Vt[n * 16 + l][kc2 * 32 + g * 8];
                    o[hd2][n] = __builtin_amdgcn_mfma_f32_16x16x32_bf16(pf, vf, o[hd2][n], 0, 0, 0);
                }
                o8[hd2] = __builtin_amdgcn_mfma_f32_16x16x32_bf16(pf, onesf, o8[hd2], 0, 0, 0);
            }
        }
    }
    // epilogue: l for row g*4+i sits in lane (g*16, reg i)
#pragma unroll
    for (int hd2 = 0; hd2 < 2; hd2++) {
        float inv[4];
#pragma unroll
        for (int i = 0; i < 4; i++) {
            float lv = __shfl(o8[hd2][i], lane & 48);
            inv[i] = 1.f / lv;
        }
#pragma unroll
        for (int n = 0; n < 8; n++) {
#pragma unroll
            for (int i = 0; i < 4; i++) {
                y[(size_t)(b * TT + q0 + g * 4 + i) * CC + (h0 + hd2) * HD + n * 16 + l] =
                    o[hd2][n][i] * inv[i];
            }
        }
    }
}

// ---------------------------------------------------------------------------
// Launcher. Workspace (~62 MB).
// ---------------------------------------------------------------------------
extern "C" void kernel_launch(void* const* d_in, const int* in_sizes, int n_in,
                              void* d_out, int out_size, void* d_ws, size_t ws_size,
                              hipStream_t stream) {
    (void)in_sizes; (void)n_in; (void)out_size; (void)ws_size;
    const float* x    = (const float*)d_in[0];
    const float* Wg   = (const float*)d_in[1];
    const float* Wqkv = (const float*)d_in[2];
    float* y = (float*)d_out;

    unsigned short* xb   = (unsigned short*)d_ws;
    unsigned short* wb   = xb + (size_t)MM * CC;
    unsigned short* qbuf = wb + (size_t)QKV_N * CC;
    unsigned short* kshB = qbuf + (size_t)MM * CC;
    unsigned short* vshT = kshB + (size_t)MM * HD;
    float* top1 = (float*)(vshT + (size_t)HD * MM);
    int*   idxb = (int*)(top1 + MM);
    int*   ord  = idxb + MM;
    int*   hs   = ord + MM;

    gate_kernel<<<MM, 256, 0, stream>>>(x, Wg, idxb, top1, xb);
    convert_bf16<<<(QKV_N * CC / 8 + 255) / 256, 256, 0, stream>>>(Wqkv, wb, QKV_N * CC / 8);
    qproj_gemm<<<dim3(16, 32), 256, 0, stream>>>(xb, wb, qbuf);
    bucket_kernel<<<1, 256, 0, stream>>>(idxb, ord, hs);
    kvsel_gemm<<<dim3(16, 2, 64), 256, 0, stream>>>(xb, wb, ord, hs, top1, kshB, vshT);
    attn_mfma<<<512, 256, 0, stream>>>(qbuf, kshB, vshT, y);
}

// Round 10
// 348.216 us; speedup vs baseline: 1.1801x; 1.0456x over previous
//
#include <hip/hip_runtime.h>
#include <math.h>
#include <cstddef>

// Problem constants
#define BB 2
#define TT 2048
#define CC 2048
#define HH 16
#define HD 128
#define MM (BB * TT)   // 4096 tokens
#define QKV_N 6144
#define BK 32

typedef __attribute__((ext_vector_type(8))) short short8;
typedef __attribute__((ext_vector_type(4))) float f32x4;

__device__ __forceinline__ unsigned short f2bf(float f) {
    union { float f; unsigned int u; } v; v.f = f;
    unsigned int r = v.u + 0x7FFFu + ((v.u >> 16) & 1u);  // RNE
    return (unsigned short)(r >> 16);
}
__device__ __forceinline__ float bf2f(unsigned short s) {
    union { unsigned int u; float f; } v; v.u = ((unsigned int)s) << 16;
    return v.f;
}
__device__ __forceinline__ void gload16(const void* g, void* l) {
    __builtin_amdgcn_global_load_lds(
        (const __attribute__((address_space(1))) unsigned int*)g,
        (__attribute__((address_space(3))) unsigned int*)l, 16, 0, 0);
}

// ---------------------------------------------------------------------------
// K1: gating (fp32, argmax ties must match np) + fused x -> bf16 conversion.
// ---------------------------------------------------------------------------
__global__ __launch_bounds__(256) void gate_kernel(const float* __restrict__ x,
                                                   const float* __restrict__ Wg,
                                                   int* __restrict__ idxbuf,
                                                   float* __restrict__ top1buf,
                                                   unsigned short* __restrict__ xb) {
    int m = blockIdx.x;
    int tid = threadIdx.x;
    int h = tid >> 4;
    int j = tid & 15;
    const float4* xr = (const float4*)(x + (size_t)m * CC);
    const float4* wr = (const float4*)(Wg + (size_t)h * CC);
    float acc = 0.f;
#pragma unroll 8
    for (int i = 0; i < CC / 4; i += 16) {
        float4 a = xr[i + j];
        float4 b = wr[i + j];
        acc += a.x * b.x + a.y * b.y + a.z * b.z + a.w * b.w;
    }
    for (int off = 8; off > 0; off >>= 1) acc += __shfl_down(acc, off, 16);
    __shared__ float logits[HH];
    if (j == 0) logits[h] = acc;
    // fused bf16 conversion of this token row (L1-hot re-read)
    {
        float4 a = xr[tid * 2], b = xr[tid * 2 + 1];
        union { unsigned short s[8]; uint4 u; } pk;
        pk.s[0] = f2bf(a.x); pk.s[1] = f2bf(a.y); pk.s[2] = f2bf(a.z); pk.s[3] = f2bf(a.w);
        pk.s[4] = f2bf(b.x); pk.s[5] = f2bf(b.y); pk.s[6] = f2bf(b.z); pk.s[7] = f2bf(b.w);
        ((uint4*)(xb + (size_t)m * CC))[tid] = pk.u;
    }
    __syncthreads();
    if (tid == 0) {
        float zmax = logits[0];
        int best = 0;
        for (int i = 1; i < HH; i++) {
            if (logits[i] > zmax) { zmax = logits[i]; best = i; }
        }
        float s = 0.f;
        for (int i = 0; i < HH; i++) s += expf(logits[i] - zmax);
        idxbuf[m] = best;
        top1buf[m] = 1.0f / s;
    }
}

// ---------------------------------------------------------------------------
// K2: fp32 -> bf16 convert (for W_qkv).
// ---------------------------------------------------------------------------
__global__ __launch_bounds__(256) void convert_bf16(const float* __restrict__ src,
                                                    unsigned short* __restrict__ dst,
                                                    int n8) {
    int i = blockIdx.x * 256 + threadIdx.x;
    if (i >= n8) return;
    const float4* s4 = (const float4*)src;
    float4 a = s4[i * 2], b = s4[i * 2 + 1];
    union { unsigned short s[8]; uint4 u; } pk;
    pk.s[0] = f2bf(a.x); pk.s[1] = f2bf(a.y); pk.s[2] = f2bf(a.z); pk.s[3] = f2bf(a.w);
    pk.s[4] = f2bf(b.x); pk.s[5] = f2bf(b.y); pk.s[6] = f2bf(b.z); pk.s[7] = f2bf(b.w);
    ((uint4*)dst)[i] = pk.u;
}

// ---------------------------------------------------------------------------
// K3: q = xb @ wb[0:2048]^T, bf16 MFMA GEMM (m97 structure), pre-scaled.
// ---------------------------------------------------------------------------
__global__ __launch_bounds__(256) void qproj_gemm(const unsigned short* __restrict__ A,  // [M][2048] bf16
                                                  const unsigned short* __restrict__ Bm, // wb [6144][2048]
                                                  unsigned short* __restrict__ C) {      // [M][2048] bf16
    __shared__ unsigned short As[128 * BK];
    __shared__ unsigned short Bs[128 * BK];
    int tid = threadIdx.x;
    int wave = tid >> 6, lane = tid & 63;
    int l = lane & 15, g = lane >> 4;
    int m0 = blockIdx.y * 128, n0 = blockIdx.x * 128;
    int wr = wave >> 1, wc = wave & 1;

    f32x4 acc[4][4];
#pragma unroll
    for (int i = 0; i < 4; i++)
#pragma unroll
        for (int j = 0; j < 4; j++) acc[i][j] = (f32x4){0.f, 0.f, 0.f, 0.f};

    int srow = lane >> 2;
    int scol = (lane & 3) * 8;
    const unsigned short* aB0 = A + (size_t)(m0 + wave * 32 + srow) * 2048 + scol;
    const unsigned short* bB0 = Bm + (size_t)(n0 + wave * 32 + srow) * 2048 + scol;
    unsigned short* aL0 = &As[wave * 1024];
    unsigned short* bL0 = &Bs[wave * 1024];

    for (int k0 = 0; k0 < 2048; k0 += BK) {
        __syncthreads();
        gload16(aB0 + k0, aL0);
        gload16(aB0 + k0 + (size_t)16 * 2048, aL0 + 512);
        gload16(bB0 + k0, bL0);
        gload16(bB0 + k0 + (size_t)16 * 2048, bL0 + 512);
        __syncthreads();
        short8 af[4], bf[4];
#pragma unroll
        for (int i = 0; i < 4; i++)
            af[i] = *(const short8*)&As[(wr * 64 + i * 16 + l) * BK + g * 8];
#pragma unroll
        for (int j = 0; j < 4; j++)
            bf[j] = *(const short8*)&Bs[(wc * 64 + j * 16 + l) * BK + g * 8];
#pragma unroll
        for (int i = 0; i < 4; i++)
#pragma unroll
            for (int j = 0; j < 4; j++)
                acc[i][j] = __builtin_amdgcn_mfma_f32_16x16x32_bf16(af[i], bf[j], acc[i][j], 0, 0, 0);
    }

    const float qscale = 0.08838834764831845f;  // 1/sqrt(128)
#pragma unroll
    for (int j = 0; j < 4; j++) {
        int col = n0 + wc * 64 + j * 16 + l;
#pragma unroll
        for (int i = 0; i < 4; i++) {
            int row = m0 + wr * 64 + i * 16 + g * 4;
#pragma unroll
            for (int r = 0; r < 4; r++)
                C[(size_t)(row + r) * CC + col] = f2bf(acc[i][j][r] * qscale);
        }
    }
}

// ---------------------------------------------------------------------------
// K4: bucket tokens by selected head (one block).
// ---------------------------------------------------------------------------
__global__ __launch_bounds__(256) void bucket_kernel(const int* __restrict__ idxb,
                                                     int* __restrict__ ord,
                                                     int* __restrict__ hs) {
    __shared__ unsigned short cnts[256][16];
    __shared__ int hsum[16], hbase[16];
    int t = threadIdx.x;
    unsigned short c[16];
#pragma unroll
    for (int h = 0; h < 16; h++) c[h] = 0;
    int hv[16];
#pragma unroll
    for (int i = 0; i < 16; i++) {
        hv[i] = idxb[t * 16 + i];
        c[hv[i]]++;
    }
#pragma unroll
    for (int h = 0; h < 16; h++) cnts[t][h] = c[h];
    __syncthreads();
    if (t < 16) {
        int s = 0;
        for (int j = 0; j < 256; j++) {
            int v = cnts[j][t];
            cnts[j][t] = (unsigned short)s;
            s += v;
        }
        hsum[t] = s;
    }
    __syncthreads();
    if (t == 0) {
        int s = 0;
        for (int h = 0; h < 16; h++) { hbase[h] = s; hs[h] = s; s += hsum[h]; }
        hs[16] = s;
    }
    __syncthreads();
    int pos[16];
#pragma unroll
    for (int h = 0; h < 16; h++) pos[h] = hbase[h] + (int)cnts[t][h];
#pragma unroll
    for (int i = 0; i < 16; i++) {
        int h = hv[i];
        ord[pos[h]++] = t * 16 + i;
    }
}

// ---------------------------------------------------------------------------
// K5: selected-head k/v projection, bucketed MFMA GEMM.
// ---------------------------------------------------------------------------
__global__ __launch_bounds__(256) void kvsel_gemm(const unsigned short* __restrict__ xb,
                                                  const unsigned short* __restrict__ wb,
                                                  const int* __restrict__ ord,
                                                  const int* __restrict__ hs,
                                                  const float* __restrict__ top1,
                                                  unsigned short* __restrict__ kshB,
                                                  unsigned short* __restrict__ vshT) {
    __shared__ unsigned short As[64 * 32];
    __shared__ unsigned short Bs[128 * 32];
    int h = blockIdx.x, reg = blockIdx.y, mt = blockIdx.z;
    int s0 = hs[h], s1 = hs[h + 1];
    int cnt = s1 - s0;
    if (mt * 64 >= cnt) return;
    int base = s0 + mt * 64;
    int tid = threadIdx.x;
    int wave = tid >> 6, lane = tid & 63;
    int l = lane & 15, g = lane >> 4;

    int arow = base + wave * 16 + (lane >> 2);
    int atok = ord[(arow < s1) ? arow : (s1 - 1)];
    const unsigned short* aSrc = xb + (size_t)atok * CC + (lane & 3) * 8;
    unsigned short* aDst = &As[wave * 512];
    int wr0 = 2048 + reg * 2048 + h * 128;
    const unsigned short* bSrc0 = wb + (size_t)(wr0 + (wave * 2 + 0) * 16 + (lane >> 2)) * CC + (lane & 3) * 8;
    const unsigned short* bSrc1 = wb + (size_t)(wr0 + (wave * 2 + 1) * 16 + (lane >> 2)) * CC + (lane & 3) * 8;
    unsigned short* bDst0 = &Bs[(wave * 2 + 0) * 512];
    unsigned short* bDst1 = &Bs[(wave * 2 + 1) * 512];

    f32x4 acc[8];
#pragma unroll
    for (int j = 0; j < 8; j++) acc[j] = (f32x4){0.f, 0.f, 0.f, 0.f};

    for (int k0 = 0; k0 < 2048; k0 += 32) {
        __syncthreads();
        gload16(aSrc + k0, aDst);
        gload16(bSrc0 + k0, bDst0);
        gload16(bSrc1 + k0, bDst1);
        __syncthreads();
        short8 af = *(const short8*)&As[(wave * 16 + l) * 32 + g * 8];
#pragma unroll
        for (int j = 0; j < 8; j++) {
            short8 bf = *(const short8*)&Bs[(j * 16 + l) * 32 + g * 8];
            acc[j] = __builtin_amdgcn_mfma_f32_16x16x32_bf16(af, bf, acc[j], 0, 0, 0);
        }
    }
#pragma unroll
    for (int i = 0; i < 4; i++) {
        int r = wave * 16 + g * 4 + i;
        if (base + r >= s1) continue;
        int tok = ord[base + r];
        if (reg == 0) {
#pragma unroll
            for (int j = 0; j < 8; j++)
                kshB[(size_t)tok * HD + j * 16 + l] = f2bf(acc[j][i]);
        } else {
            float tv = top1[tok];
#pragma unroll
            for (int j = 0; j < 8; j++)
                vshT[(size_t)(j * 16 + l) * MM + tok] = f2bf(acc[j][i] * tv);
        }
    }
}

// ---------------------------------------------------------------------------
// K6: MFMA bf16 flash attention, complement-paired q-tiles for perfect
// balance. Block = (pair(ql,127-ql), b, head-quarter): 512 blocks, each
// EXACTLY 33 chunks. One head per wave, two q-tiles per wave: K/V frags
// read from LDS once, feed both combos (dual Ps). Same two-barrier staging
// and same-wave Ps discipline as the validated R6/R9 body. exp streamed
// per key-tile to keep VGPR below the scratch cliff (R7 lesson).
// ---------------------------------------------------------------------------
__global__ __launch_bounds__(256) void attn_mfma(const unsigned short* __restrict__ qb,   // [M][2048] bf16, q pre-scaled
                                                 const unsigned short* __restrict__ kb,   // [M][128] bf16
                                                 const unsigned short* __restrict__ vtb,  // [128][M] bf16
                                                 float* __restrict__ y) {                 // [M][2048] fp32
    __shared__ unsigned short Ks[64][136];        // 17408 B
    __shared__ unsigned short Vt[128][72];        // 18432 B
    __shared__ unsigned short Ps[4][2][16][72];   // 18432 B (per-wave, 2 q-tiles)

    int bid = blockIdx.x;                 // 512 blocks
    int ql = 64 + (bid >> 3);             // long q-tile: 64..127
    int b  = (bid >> 2) & 1;
    int hq = bid & 3;                     // head quarter
    int qs = 127 - ql;                    // short q-tile: 0..63
    int q0l = ql * 16, q0s = qs * 16;
    int nchL = (ql >> 2) + 1;             // 17..32
    int nchS = (qs >> 2) + 1;             // 1..16  (nchL + nchS == 33)
    int tid = threadIdx.x;
    int wave = tid >> 6;
    int lane = tid & 63;
    int l = lane & 15;
    int g = lane >> 4;
    int h = hq * 4 + wave;                // one head per wave

    // Q a-frags for both q-tiles (bf16, pre-scaled)
    short8 qf[2][4];
#pragma unroll
    for (int qt = 0; qt < 2; qt++) {
        int q0 = qt ? q0s : q0l;
        const unsigned short* qrow = qb + (size_t)(b * TT + q0 + l) * CC + h * HD;
#pragma unroll
        for (int kc = 0; kc < 4; kc++)
            qf[qt][kc] = *(const short8*)(qrow + kc * 32 + g * 8);
    }

    // ones-column B-frag: B[n][k] = (n==0) ? 1 : 0
    short8 onesf;
    {
        short v = (l == 0) ? (short)0x3F80 : (short)0;
#pragma unroll
        for (int e = 0; e < 8; e++) onesf[e] = v;
    }

    f32x4 o[2][8];
    f32x4 o8[2];
#pragma unroll
    for (int qt = 0; qt < 2; qt++) {
#pragma unroll
        for (int n = 0; n < 8; n++) o[qt][n] = (f32x4){0.f, 0.f, 0.f, 0.f};
        o8[qt] = (f32x4){0.f, 0.f, 0.f, 0.f};
    }

    const unsigned short* kbase = kb + (size_t)b * TT * HD;
    int rbaseL = q0l + g * 4;
    int rbaseS = q0s + g * 4;

    for (int c = 0; c < nchL; c++) {
        int kc0 = c * 64;
        __syncthreads();   // previous chunk's LDS reads done
        // stage K: 64 keys x 128 dims, 1024 uint4, coalesced (1KB rows)
#pragma unroll
        for (int rep = 0; rep < 4; rep++) {
            int f = tid + rep * 256;
            int row = f >> 4, c8 = f & 15;
            *(uint4*)&Ks[row][c8 * 8] =
                *(const uint4*)(kbase + (size_t)(kc0 + row) * HD + c8 * 8);
        }
        // stage Vt: 128 dims x 64 keys (transposed source, 128B segments)
#pragma unroll
        for (int rep = 0; rep < 4; rep++) {
            int f = tid + rep * 256;
            int dd = f >> 3, k8 = f & 7;
            *(uint4*)&Vt[dd][k8 * 8] =
                *(const uint4*)(vtb + (size_t)dd * MM + b * TT + kc0 + k8 * 8);
        }
        __syncthreads();
        bool sAct = (c < nchS);           // short tile active this chunk
        bool diagL = (c == nchL - 1);
        bool diagS = (c == nchS - 1);

        // S = Q K^T, streamed per 16-key tile; K frags read ONCE per tile.
#pragma unroll
        for (int t = 0; t < 4; t++) {
            short8 kf[4];
#pragma unroll
            for (int kc = 0; kc < 4; kc++)
                kf[kc] = *(const short8*)&Ks[t * 16 + l][kc * 32 + g * 8];
            f32x4 sl = (f32x4){0.f, 0.f, 0.f, 0.f};
#pragma unroll
            for (int kc = 0; kc < 4; kc++)
                sl = __builtin_amdgcn_mfma_f32_16x16x32_bf16(qf[0][kc], kf[kc], sl, 0, 0, 0);
            if (diagL) {
                int key = kc0 + t * 16 + l;
#pragma unroll
                for (int i = 0; i < 4; i++)
                    if (key > rbaseL + i) sl[i] = -1e30f;
            }
#pragma unroll
            for (int i = 0; i < 4; i++)
                Ps[wave][0][g * 4 + i][t * 16 + l] = f2bf(__expf(sl[i] - 30.f));
            if (sAct) {
                f32x4 ss = (f32x4){0.f, 0.f, 0.f, 0.f};
#pragma unroll
                for (int kc = 0; kc < 4; kc++)
                    ss = __builtin_amdgcn_mfma_f32_16x16x32_bf16(qf[1][kc], kf[kc], ss, 0, 0, 0);
                if (diagS) {
                    int key = kc0 + t * 16 + l;
#pragma unroll
                    for (int i = 0; i < 4; i++)
                        if (key > rbaseS + i) ss[i] = -1e30f;
                }
#pragma unroll
                for (int i = 0; i < 4; i++)
                    Ps[wave][1][g * 4 + i][t * 16 + l] = f2bf(__expf(ss[i] - 30.f));
            }
        }
        // O += P V ; l += P.  V frags read ONCE, feed both combos.
#pragma unroll
        for (int kc2 = 0; kc2 < 2; kc2++) {
            short8 pf0 = *(const short8*)&Ps[wave][0][l][kc2 * 32 + g * 8];
            if (sAct) {
                short8 pf1 = *(const short8*)&Ps[wave][1][l][kc2 * 32 + g * 8];
#pragma unroll
                for (int n = 0; n < 8; n++) {
                    short8 vf = *(const short8*)&Vt[n * 16 + l][kc2 * 32 + g * 8];
                    o[0][n] = __builtin_amdgcn_mfma_f32_16x16x32_bf16(pf0, vf, o[0][n], 0, 0, 0);
                    o[1][n] = __builtin_amdgcn_mfma_f32_16x16x32_bf16(pf1, vf, o[1][n], 0, 0, 0);
                }
                o8[0] = __builtin_amdgcn_mfma_f32_16x16x32_bf16(pf0, onesf, o8[0], 0, 0, 0);
                o8[1] = __builtin_amdgcn_mfma_f32_16x16x32_bf16(pf1, onesf, o8[1], 0, 0, 0);
            } else {
#pragma unroll
                for (int n = 0; n < 8; n++) {
                    short8 vf = *(const short8*)&Vt[n * 16 + l][kc2 * 32 + g * 8];
                    o[0][n] = __builtin_amdgcn_mfma_f32_16x16x32_bf16(pf0, vf, o[0][n], 0, 0, 0);
                }
                o8[0] = __builtin_amdgcn_mfma_f32_16x16x32_bf16(pf0, onesf, o8[0], 0, 0, 0);
            }
        }
    }
    // epilogue: normalize both q-tiles; l for row g*4+i sits in lane (g*16, reg i)
#pragma unroll
    for (int qt = 0; qt < 2; qt++) {
        int q0 = qt ? q0s : q0l;
        float inv[4];
#pragma unroll
        for (int i = 0; i < 4; i++) {
            float lv = __shfl(o8[qt][i], lane & 48);
            inv[i] = 1.f / lv;
        }
#pragma unroll
        for (int n = 0; n < 8; n++) {
#pragma unroll
            for (int i = 0; i < 4; i++) {
                y[(size_t)(b * TT + q0 + g * 4 + i) * CC + h * HD + n * 16 + l] =
                    o[qt][n][i] * inv[i];
            }
        }
    }
}

// ---------------------------------------------------------------------------
// Launcher. Workspace (~62 MB).
// ---------------------------------------------------------------------------
extern "C" void kernel_launch(void* const* d_in, const int* in_sizes, int n_in,
                              void* d_out, int out_size, void* d_ws, size_t ws_size,
                              hipStream_t stream) {
    (void)in_sizes; (void)n_in; (void)out_size; (void)ws_size;
    const float* x    = (const float*)d_in[0];
    const float* Wg   = (const float*)d_in[1];
    const float* Wqkv = (const float*)d_in[2];
    float* y = (float*)d_out;

    unsigned short* xb   = (unsigned short*)d_ws;
    unsigned short* wb   = xb + (size_t)MM * CC;
    unsigned short* qbuf = wb + (size_t)QKV_N * CC;
    unsigned short* kshB = qbuf + (size_t)MM * CC;
    unsigned short* vshT = kshB + (size_t)MM * HD;
    float* top1 = (float*)(vshT + (size_t)HD * MM);
    int*   idxb = (int*)(top1 + MM);
    int*   ord  = idxb + MM;
    int*   hs   = ord + MM;

    gate_kernel<<<MM, 256, 0, stream>>>(x, Wg, idxb, top1, xb);
    convert_bf16<<<(QKV_N * CC / 8 + 255) / 256, 256, 0, stream>>>(Wqkv, wb, QKV_N * CC / 8);
    qproj_gemm<<<dim3(16, 32), 256, 0, stream>>>(xb, wb, qbuf);
    bucket_kernel<<<1, 256, 0, stream>>>(idxb, ord, hs);
    kvsel_gemm<<<dim3(16, 2, 64), 256, 0, stream>>>(xb, wb, ord, hs, top1, kshB, vshT);
    attn_mfma<<<512, 256, 0, stream>>>(qbuf, kshB, vshT, y);
}